// Round 8
// baseline (217.406 us; speedup 1.0000x reference)
//
#include <hip/hip_runtime.h>
#include <float.h>

// VQ: B=32, C=64, H=64, W=64, N_EMBED=512
#define C_DIM   64
#define K_CODES 512
#define HW_BITS 12            // HW = 4096
#define N_TOK   131072
#define WAVES   4
#define KPW     (K_CODES / WAVES)   // 128 codes per wave

typedef float f4 __attribute__((ext_vector_type(4)));

// Prep: transpose embed [C][K] -> eT [K][C], and norms[k] = ||e_k||^2.
__global__ __launch_bounds__(256) void vq_prep(const float* __restrict__ embed,
                                               float* __restrict__ eT,
                                               float* __restrict__ norms) {
    int k = blockIdx.x * blockDim.x + threadIdx.x;
    if (k >= K_CODES) return;
    float s = 0.f;
    #pragma unroll
    for (int c = 0; c < C_DIM; ++c) {
        float v = embed[c * K_CODES + k];   // coalesced across k
        eT[k * C_DIM + c] = v;
        s = fmaf(v, v, s);
    }
    norms[k] = s;
}

// Round-7 structure (lane=token, wave w scans codes [128w,128w+128) via
// wave-uniform s_load) + the residency hammer: all 16 f-quads pass through
// one volatile asm, so the k-loop consumes asm outputs — the scheduler can
// no longer sink/rematerialize the f loads into the loop.
__global__ __launch_bounds__(256, 2) void vq_main(const float* __restrict__ x,
                                                  const float* __restrict__ eT,
                                                  const float* __restrict__ norms,
                                                  float* __restrict__ out_qwg,
                                                  float* __restrict__ out_q,
                                                  float* __restrict__ out_ind) {
    const int lane = threadIdx.x & 63;
    const int wvu  = __builtin_amdgcn_readfirstlane((int)(threadIdx.x >> 6)); // uniform
    const int tok  = (blockIdx.x << 6) + lane;
    const int b    = tok >> HW_BITS;
    const int hw   = tok & ((1 << HW_BITS) - 1);

    const float* xb = x + ((size_t)b << 18) + hw;   // b*C*HW + hw, per-lane

    // f in 16 named quads: f<Q> holds channels 4Q..4Q+3 (loads coalesced).
    f4 f0, f1, f2, f3, f4_, f5, f6, f7, f8, f9, f10, f11, f12, f13, f14, f15;
#define LOADF(V, Q)                                          \
    V = (f4){xb[(size_t)(4 * Q + 0) << HW_BITS],             \
             xb[(size_t)(4 * Q + 1) << HW_BITS],             \
             xb[(size_t)(4 * Q + 2) << HW_BITS],             \
             xb[(size_t)(4 * Q + 3) << HW_BITS]}
    LOADF(f0, 0);  LOADF(f1, 1);  LOADF(f2, 2);  LOADF(f3, 3);
    LOADF(f4_, 4); LOADF(f5, 5);  LOADF(f6, 6);  LOADF(f7, 7);
    LOADF(f8, 8);  LOADF(f9, 9);  LOADF(f10, 10); LOADF(f11, 11);
    LOADF(f12, 12); LOADF(f13, 13); LOADF(f14, 14); LOADF(f15, 15);
#undef LOADF

    // Residency pin: k-loop FMAs consume THESE outputs; volatile asm cannot
    // be sunk or duplicated -> f must stay in VGPRs (spill would show in
    // WRITE_SIZE; budget is 256 under launch_bounds(256,2)).
    asm volatile(""
        : "+v"(f0), "+v"(f1), "+v"(f2), "+v"(f3),
          "+v"(f4_), "+v"(f5), "+v"(f6), "+v"(f7),
          "+v"(f8), "+v"(f9), "+v"(f10), "+v"(f11),
          "+v"(f12), "+v"(f13), "+v"(f14), "+v"(f15));

    const int    k0    = wvu * KPW;
    const float* eBase = eT + ((size_t)k0 << 6);    // wave-uniform -> s_load path
    const float* nBase = norms + k0;

    float best  = FLT_MAX;
    int   bestk = k0;
    #pragma unroll 2
    for (int kk = 0; kk < KPW; ++kk) {
        const float* e = eBase + (kk << 6);   // uniform -> scalar loads
        float d0 = 0.f, d1 = 0.f, d2 = 0.f, d3 = 0.f;
        // chains = c mod 4, ascending c: bit-identical to rounds 1-3/7
#define STEP(V, Q)                                \
        d0 = fmaf(V.x, e[4 * Q + 0], d0);         \
        d1 = fmaf(V.y, e[4 * Q + 1], d1);         \
        d2 = fmaf(V.z, e[4 * Q + 2], d2);         \
        d3 = fmaf(V.w, e[4 * Q + 3], d3);
        STEP(f0, 0)  STEP(f1, 1)  STEP(f2, 2)  STEP(f3, 3)
        STEP(f4_, 4) STEP(f5, 5)  STEP(f6, 6)  STEP(f7, 7)
        STEP(f8, 8)  STEP(f9, 9)  STEP(f10, 10) STEP(f11, 11)
        STEP(f12, 12) STEP(f13, 13) STEP(f14, 14) STEP(f15, 15)
#undef STEP
        float dot   = (d0 + d1) + (d2 + d3);
        float score = fmaf(-2.f, dot, nBase[kk]);   // same formula as r1-r7
        if (score < best) { best = score; bestk = k0 + kk; }  // strict < = first min
    }

    __shared__ float sS[WAVES][64];
    __shared__ int   sI[WAVES][64];
    sS[wvu][lane] = best;
    sI[wvu][lane] = bestk;
    __syncthreads();

    // every thread recomputes the global winner (deterministic, all agree)
    float gb = sS[0][lane];
    int   gk = sI[0][lane];
    #pragma unroll
    for (int w = 1; w < WAVES; ++w) {       // compile-time w, ascending chunks
        float s = sS[w][lane];
        int   i = sI[w][lane];
        if (s < gb) { gb = s; gk = i; }     // strict < = first min
    }

    // epilogue: wave wvu writes channels [16*wvu, 16*wvu+16) for its token.
    const f4* eq4 = (const f4*)(eT + ((size_t)gk << 6)) + (wvu << 2);
    float* o0 = out_qwg + ((size_t)b << 18) + hw;
    float* o1 = out_q   + ((size_t)b << 18) + hw;

#define EPI4(J, V, CB0)                                                     \
    {                                                                       \
        f4 qv = eq4[J];                                                     \
        f4 ff = V;                                                          \
        o0[(size_t)((CB0) + 4 * J + 0) << HW_BITS] = ff.x + (qv.x - ff.x);  \
        o0[(size_t)((CB0) + 4 * J + 1) << HW_BITS] = ff.y + (qv.y - ff.y);  \
        o0[(size_t)((CB0) + 4 * J + 2) << HW_BITS] = ff.z + (qv.z - ff.z);  \
        o0[(size_t)((CB0) + 4 * J + 3) << HW_BITS] = ff.w + (qv.w - ff.w);  \
        o1[(size_t)((CB0) + 4 * J + 0) << HW_BITS] = qv.x;                  \
        o1[(size_t)((CB0) + 4 * J + 1) << HW_BITS] = qv.y;                  \
        o1[(size_t)((CB0) + 4 * J + 2) << HW_BITS] = qv.z;                  \
        o1[(size_t)((CB0) + 4 * J + 3) << HW_BITS] = qv.w;                  \
    }

    if (wvu == 0) {
        EPI4(0, f0, 0)  EPI4(1, f1, 0)  EPI4(2, f2, 0)  EPI4(3, f3, 0)
        out_ind[tok] = (float)gk;
    } else if (wvu == 1) {
        EPI4(0, f4_, 16)  EPI4(1, f5, 16)  EPI4(2, f6, 16)  EPI4(3, f7, 16)
    } else if (wvu == 2) {
        EPI4(0, f8, 32)  EPI4(1, f9, 32)  EPI4(2, f10, 32)  EPI4(3, f11, 32)
    } else {
        EPI4(0, f12, 48)  EPI4(1, f13, 48)  EPI4(2, f14, 48)  EPI4(3, f15, 48)
    }
#undef EPI4
}

extern "C" void kernel_launch(void* const* d_in, const int* in_sizes, int n_in,
                              void* d_out, int out_size, void* d_ws, size_t ws_size,
                              hipStream_t stream) {
    const float* x     = (const float*)d_in[0];
    const float* embed = (const float*)d_in[1];

    float* out     = (float*)d_out;
    float* out_qwg = out;                       // 8388608 f32
    float* out_q   = out + (size_t)8388608;     // 8388608 f32
    float* out_ind = out + (size_t)16777216;    // 131072 f32

    float* eT    = (float*)d_ws;                // 512*64 f32 = 128 KB
    float* norms = eT + K_CODES * C_DIM;        // 512 f32

    vq_prep<<<2, 256, 0, stream>>>(embed, eT, norms);
    vq_main<<<N_TOK / 64, 256, 0, stream>>>(x, eT, norms, out_qwg, out_q, out_ind);
}